// Round 15
// baseline (39.188 us; speedup 1.0000x reference)
//
#include <hip/hip_runtime.h>
#include <hip/hip_bf16.h>

#define BDIM 512

typedef __attribute__((ext_vector_type(8))) _Float16 f16x8;
typedef __attribute__((ext_vector_type(4))) _Float16 f16x4;
typedef __attribute__((ext_vector_type(4))) float f32x4;

// native v_exp_f32 computes 2^x; __exp2f doesn't exist in HIP
#define EXP2F(x) __builtin_amdgcn_exp2f(x)

// Local windowed attention with RoPE. b=32, n=4096, d=64, WINDOW=128, 1 backward window.
// R15: MAX-OCCUPANCY structure. One window per block, 512 threads (8 waves, each wave
// one 16-row m-tile), SINGLE 36.3KB K/V slot staged sequentially (half0 = previous
// window, half1 = own window). Grid 1024 = 4 blocks/CU, launch_bounds(512,8) -> VGPR
// cap 64 -> 32 waves/CU (8/SIMD), 2x R13's latency hiding. R11's version of this bet
// failed because 256-thread blocks gave the SAME 16 waves/CU as R13; this is the
// untested 32-wave cell. Accepted costs: FETCH back to ~81MB (no pair-sharing), +33%
// staging phases -- the bet is latency hiding dominates (all pipes <30% in R13).
// Carried from R13 (33.2us best): swapped QK^T (stats c-layout, accO row-layout,
// factors shuffled c->row), permuted Vt columns (PV B = one ds_read_b128), exp2-domain
// online softmax with defer-rescale, causal chunk1 skip (waves 0-3), Q loads issued
// before staging. Spill sentinel: WRITE_SIZE == output 32.8MB.
__global__ __launch_bounds__(512, 8)
void la_kernel(const float* __restrict__ qg, const float* __restrict__ kg,
               const float* __restrict__ vg, float* __restrict__ outg)
{
    __shared__ _Float16 Ks[128][72];   // 18432 B
    __shared__ _Float16 Vt[64][140];   // 17920 B  -> 36352 B total

    const int ww = blockIdx.x, bb = blockIdx.y;
    const int tid = threadIdx.x;
    const int wv = tid >> 6, lane = tid & 63, g = lane >> 4, c = lane & 15;
    const float NEG = -3.0e38f;
    const float NLT32 = -0.28782313662425572f;   // -ln(10000)/32
    const float QSCALE = 0.125f * 1.4426950408889634f;  // d^-0.5 * log2(e)
    const size_t rowb = (size_t)bb * 4096;
    const int srow0 = ww * 128 - 128;            // source row of half0, j=0

    // hoisted inverse frequencies
    const int cbK = (tid & 7) << 2;
    float invfK[4];
    #pragma unroll
    for (int u = 0; u < 4; ++u) invfK[u] = __expf((float)(cbK + u) * NLT32);
    float invfQ[8];
    #pragma unroll
    for (int u = 0; u < 8; ++u) invfQ[u] = __expf((float)(8 * g + u) * NLT32);

    const int jqV = tid >> 4, eqV = tid & 15;
    const int colbV = ((jqV & 24) << 2) + 8 * (jqV & 3) + 4 * ((jqV >> 2) & 1);

    const int qrow = wv * 16 + c;

    // ---- stage half h (K: RoPE t = 128h + j; V: permuted transpose) ----
    auto stage = [&](int h) {
        #pragma unroll
        for (int it = 0; it < 2; ++it) {
            int j = (tid + it * 512) >> 3;       // 0..127
            int t = 128 * h + j;
            const float* p = kg + (rowb + srow0 + t) * 64 + cbK;
            float4 x1 = *(const float4*)p;
            float4 x2 = *(const float4*)(p + 32);
            const float* x1p = &x1.x;
            const float* x2p = &x2.x;
            f16x4 lo, hi;
            #pragma unroll
            for (int u = 0; u < 4; ++u) {
                float sn, cs; __sincosf((float)t * invfK[u], &sn, &cs);
                lo[u] = (_Float16)(x1p[u] * cs - x2p[u] * sn);
                hi[u] = (_Float16)(x2p[u] * cs + x1p[u] * sn);
            }
            *(f16x4*)&Ks[j][cbK]      = lo;
            *(f16x4*)&Ks[j][cbK + 32] = hi;
        }
        float4 x[4];
        #pragma unroll
        for (int w = 0; w < 4; ++w)
            x[w] = *(const float4*)(vg + (rowb + srow0 + 128 * h + 4 * jqV + w) * 64 + 4 * eqV);
        #pragma unroll
        for (int u = 0; u < 4; ++u) {
            f16x4 o;
            o[0] = (_Float16)((const float*)&x[0])[u];
            o[1] = (_Float16)((const float*)&x[1])[u];
            o[2] = (_Float16)((const float*)&x[2])[u];
            o[3] = (_Float16)((const float*)&x[3])[u];
            *(f16x4*)&Vt[4 * eqV + u][colbV] = o;
        }
    };

    // ---- flash state (m, s in c-layout; accO in row-layout) ----
    f32x4 accO[4];
    #pragma unroll
    for (int nt = 0; nt < 4; ++nt) accO[nt] = (f32x4){0.f,0.f,0.f,0.f};
    float m = NEG, s = 0.f;

    // ---- compute one staged half; causal => mask local jj > qrow ----
    auto computeHalf = [&](bool causal, f16x8 qa0, f16x8 qa1) {
        #pragma unroll
        for (int ch = 0; ch < 2; ++ch) {
            // exact skip: causal chunk1 fully masked for waves 0-3 (qrow <= 63)
            if (causal && ch == 1 && wv < 4) continue;

            f32x4 acc[4];
            #pragma unroll
            for (int jt = 0; jt < 4; ++jt) acc[jt] = (f32x4){0.f,0.f,0.f,0.f};

            #pragma unroll
            for (int jt = 0; jt < 4; ++jt) {
                int row = ch * 64 + jt * 16 + c;
                f16x8 kb0 = *(const f16x8*)&Ks[row][8 * g];
                f16x8 kb1 = *(const f16x8*)&Ks[row][32 + 8 * g];
                acc[jt] = __builtin_amdgcn_mfma_f32_16x16x32_f16(kb0, qa0, acc[jt], 0, 0, 0);
                acc[jt] = __builtin_amdgcn_mfma_f32_16x16x32_f16(kb1, qa1, acc[jt], 0, 0, 0);
            }

            if (causal) {
                #pragma unroll
                for (int jt = 0; jt < 4; ++jt)
                    #pragma unroll
                    for (int r = 0; r < 4; ++r) {
                        int jj = ch * 64 + jt * 16 + 4 * g + r;
                        if (jj > qrow) acc[jt][r] = NEG;
                    }
            }

            float mx = NEG;
            #pragma unroll
            for (int jt = 0; jt < 4; ++jt)
                #pragma unroll
                for (int r = 0; r < 4; ++r) mx = fmaxf(mx, acc[jt][r]);
            mx = fmaxf(mx, __shfl_xor(mx, 16));
            mx = fmaxf(mx, __shfl_xor(mx, 32));

            const bool grow = !__all(mx <= m);   // wave-uniform
            float mnew = grow ? fmaxf(m, mx) : m;

            float ps = 0.f;
            f16x8 pa[2];
            #pragma unroll
            for (int jt = 0; jt < 4; ++jt)
                #pragma unroll
                for (int r = 0; r < 4; ++r) {
                    float p = EXP2F(acc[jt][r] - mnew);    // masked -> 0
                    ps += p;
                    pa[jt >> 1][(jt & 1) * 4 + r] = (_Float16)p;
                }
            ps += __shfl_xor(ps, 16);
            ps += __shfl_xor(ps, 32);

            if (grow) {
                float alpha = EXP2F(m - mnew);   // first real chunk -> 0
                s = s * alpha + ps;
                m = mnew;
                float alphaD[4];
                #pragma unroll
                for (int r = 0; r < 4; ++r)
                    alphaD[r] = __shfl(alpha, (lane & 48) | (4 * g + r));
                #pragma unroll
                for (int nt = 0; nt < 4; ++nt)
                    #pragma unroll
                    for (int r = 0; r < 4; ++r) accO[nt][r] *= alphaD[r];
            } else {
                s += ps;
            }

            #pragma unroll
            for (int st = 0; st < 2; ++st) {
                #pragma unroll
                for (int nt = 0; nt < 4; ++nt) {
                    f16x8 vb = *(const f16x8*)&Vt[nt * 16 + c][ch * 64 + st * 32 + 8 * g];
                    accO[nt] = __builtin_amdgcn_mfma_f32_16x16x32_f16(pa[st], vb, accO[nt], 0, 0, 0);
                }
            }
        }
    };

    // ---- schedule: Qraw -> stage(h0) -> ropeQ -> sync -> compute(h0) -> sync ->
    //      stage(h1) -> sync -> compute(h1, causal) -> epilogue ----
    float4 qr[4];
    {
        const float* p = qg + (rowb + ww * 128 + qrow) * 64 + 8 * g;
        qr[0] = *(const float4*)p;
        qr[1] = *(const float4*)(p + 4);
        qr[2] = *(const float4*)(p + 32);
        qr[3] = *(const float4*)(p + 36);
    }

    if (ww != 0) stage(0);

    f16x8 qA, qB;
    {
        const float tq = (float)(128 + qrow);
        float ra[8] = {qr[0].x,qr[0].y,qr[0].z,qr[0].w,qr[1].x,qr[1].y,qr[1].z,qr[1].w};
        float rb[8] = {qr[2].x,qr[2].y,qr[2].z,qr[2].w,qr[3].x,qr[3].y,qr[3].z,qr[3].w};
        #pragma unroll
        for (int u = 0; u < 8; ++u) {
            float sn, cs; __sincosf(tq * invfQ[u], &sn, &cs);
            float a = ra[u] * QSCALE, b = rb[u] * QSCALE;
            qA[u] = (_Float16)(a * cs - b * sn);
            qB[u] = (_Float16)(b * cs + a * sn);
        }
    }

    if (ww != 0) {
        __syncthreads();
        computeHalf(false, qA, qB);
        __syncthreads();                 // slot reads done before overwrite
    }

    stage(1);
    __syncthreads();
    computeHalf(true, qA, qB);

    // ---- epilogue: 1/s (c-layout) -> row-layout, store ----
    float rcp = 1.0f / s;
    float rcpD[4];
    #pragma unroll
    for (int r = 0; r < 4; ++r)
        rcpD[r] = __shfl(rcp, (lane & 48) | (4 * g + r));

    float* op = outg + (rowb + ww * 128 + wv * 16) * 64;
    #pragma unroll
    for (int nt = 0; nt < 4; ++nt)
        #pragma unroll
        for (int r = 0; r < 4; ++r)
            op[(size_t)(4 * g + r) * 64 + nt * 16 + c] = accO[nt][r] * rcpD[r];
}

extern "C" void kernel_launch(void* const* d_in, const int* in_sizes, int n_in,
                              void* d_out, int out_size, void* d_ws, size_t ws_size,
                              hipStream_t stream) {
    (void)in_sizes; (void)n_in; (void)out_size; (void)d_ws; (void)ws_size;
    const float* q = (const float*)d_in[0];
    const float* k = (const float*)d_in[1];
    const float* v = (const float*)d_in[2];
    float* out = (float*)d_out;
    dim3 grid(32, 32);  // x = window, y = batch
    la_kernel<<<grid, BDIM, 0, stream>>>(q, k, v, out);
}

// Round 16
// 38.008 us; speedup vs baseline: 1.0311x; 1.0311x over previous
//
#include <hip/hip_runtime.h>
#include <hip/hip_bf16.h>

#define BDIM 512

typedef __attribute__((ext_vector_type(8))) _Float16 f16x8;
typedef __attribute__((ext_vector_type(4))) _Float16 f16x4;
typedef __attribute__((ext_vector_type(4))) float f32x4;

// native v_exp_f32 computes 2^x; __exp2f doesn't exist in HIP
#define EXP2F(x) __builtin_amdgcn_exp2f(x)

// Local windowed attention with RoPE. b=32, n=4096, d=64, WINDOW=128, 1 backward window.
// R16 = R15 structure with launch_bounds(512,6): the no-spill occupancy cell.
// R15 evidence: (512,8) -> VGPR 32, 14MB spill, 57% occ, 39us (spill dominates).
// R13 evidence: (512,4) -> VGPR 52, no spill, 30% occ, 33.2us (latency-bound).
// (512,6) caps VGPR at ~85 >> 52 needed -> 3 blocks/CU x 8 waves = 24 waves/CU.
// One window per block, 512 threads (8 waves x one 16-row m-tile), single 36.3KB
// K/V slot staged sequentially (half0 = previous window, half1 = own).
// Carried: swapped QK^T (stats c-layout, accO row-layout, factors shuffled c->row),
// permuted Vt columns (PV B = one ds_read_b128), exp2-domain online softmax with
// defer-rescale, causal chunk1 skip (waves 0-3), Q loads issued before staging.
// Spill sentinel: WRITE_SIZE == output 32.8MB.
__global__ __launch_bounds__(512, 6)
void la_kernel(const float* __restrict__ qg, const float* __restrict__ kg,
               const float* __restrict__ vg, float* __restrict__ outg)
{
    __shared__ _Float16 Ks[128][72];   // 18432 B
    __shared__ _Float16 Vt[64][140];   // 17920 B  -> 36352 B total

    const int ww = blockIdx.x, bb = blockIdx.y;
    const int tid = threadIdx.x;
    const int wv = tid >> 6, lane = tid & 63, g = lane >> 4, c = lane & 15;
    const float NEG = -3.0e38f;
    const float NLT32 = -0.28782313662425572f;   // -ln(10000)/32
    const float QSCALE = 0.125f * 1.4426950408889634f;  // d^-0.5 * log2(e)
    const size_t rowb = (size_t)bb * 4096;
    const int srow0 = ww * 128 - 128;            // source row of half0, j=0

    // hoisted inverse frequencies
    const int cbK = (tid & 7) << 2;
    float invfK[4];
    #pragma unroll
    for (int u = 0; u < 4; ++u) invfK[u] = __expf((float)(cbK + u) * NLT32);
    float invfQ[8];
    #pragma unroll
    for (int u = 0; u < 8; ++u) invfQ[u] = __expf((float)(8 * g + u) * NLT32);

    const int jqV = tid >> 4, eqV = tid & 15;
    const int colbV = ((jqV & 24) << 2) + 8 * (jqV & 3) + 4 * ((jqV >> 2) & 1);

    const int qrow = wv * 16 + c;

    // ---- stage half h (K: RoPE t = 128h + j; V: permuted transpose) ----
    auto stage = [&](int h) {
        #pragma unroll
        for (int it = 0; it < 2; ++it) {
            int j = (tid + it * 512) >> 3;       // 0..127
            int t = 128 * h + j;
            const float* p = kg + (rowb + srow0 + t) * 64 + cbK;
            float4 x1 = *(const float4*)p;
            float4 x2 = *(const float4*)(p + 32);
            const float* x1p = &x1.x;
            const float* x2p = &x2.x;
            f16x4 lo, hi;
            #pragma unroll
            for (int u = 0; u < 4; ++u) {
                float sn, cs; __sincosf((float)t * invfK[u], &sn, &cs);
                lo[u] = (_Float16)(x1p[u] * cs - x2p[u] * sn);
                hi[u] = (_Float16)(x2p[u] * cs + x1p[u] * sn);
            }
            *(f16x4*)&Ks[j][cbK]      = lo;
            *(f16x4*)&Ks[j][cbK + 32] = hi;
        }
        float4 x[4];
        #pragma unroll
        for (int w = 0; w < 4; ++w)
            x[w] = *(const float4*)(vg + (rowb + srow0 + 128 * h + 4 * jqV + w) * 64 + 4 * eqV);
        #pragma unroll
        for (int u = 0; u < 4; ++u) {
            f16x4 o;
            o[0] = (_Float16)((const float*)&x[0])[u];
            o[1] = (_Float16)((const float*)&x[1])[u];
            o[2] = (_Float16)((const float*)&x[2])[u];
            o[3] = (_Float16)((const float*)&x[3])[u];
            *(f16x4*)&Vt[4 * eqV + u][colbV] = o;
        }
    };

    // ---- flash state (m, s in c-layout; accO in row-layout) ----
    f32x4 accO[4];
    #pragma unroll
    for (int nt = 0; nt < 4; ++nt) accO[nt] = (f32x4){0.f,0.f,0.f,0.f};
    float m = NEG, s = 0.f;

    // ---- compute one staged half; causal => mask local jj > qrow ----
    auto computeHalf = [&](bool causal, f16x8 qa0, f16x8 qa1) {
        #pragma unroll
        for (int ch = 0; ch < 2; ++ch) {
            // exact skip: causal chunk1 fully masked for waves 0-3 (qrow <= 63)
            if (causal && ch == 1 && wv < 4) continue;

            f32x4 acc[4];
            #pragma unroll
            for (int jt = 0; jt < 4; ++jt) acc[jt] = (f32x4){0.f,0.f,0.f,0.f};

            #pragma unroll
            for (int jt = 0; jt < 4; ++jt) {
                int row = ch * 64 + jt * 16 + c;
                f16x8 kb0 = *(const f16x8*)&Ks[row][8 * g];
                f16x8 kb1 = *(const f16x8*)&Ks[row][32 + 8 * g];
                acc[jt] = __builtin_amdgcn_mfma_f32_16x16x32_f16(kb0, qa0, acc[jt], 0, 0, 0);
                acc[jt] = __builtin_amdgcn_mfma_f32_16x16x32_f16(kb1, qa1, acc[jt], 0, 0, 0);
            }

            if (causal) {
                #pragma unroll
                for (int jt = 0; jt < 4; ++jt)
                    #pragma unroll
                    for (int r = 0; r < 4; ++r) {
                        int jj = ch * 64 + jt * 16 + 4 * g + r;
                        if (jj > qrow) acc[jt][r] = NEG;
                    }
            }

            float mx = NEG;
            #pragma unroll
            for (int jt = 0; jt < 4; ++jt)
                #pragma unroll
                for (int r = 0; r < 4; ++r) mx = fmaxf(mx, acc[jt][r]);
            mx = fmaxf(mx, __shfl_xor(mx, 16));
            mx = fmaxf(mx, __shfl_xor(mx, 32));

            const bool grow = !__all(mx <= m);   // wave-uniform
            float mnew = grow ? fmaxf(m, mx) : m;

            float ps = 0.f;
            f16x8 pa[2];
            #pragma unroll
            for (int jt = 0; jt < 4; ++jt)
                #pragma unroll
                for (int r = 0; r < 4; ++r) {
                    float p = EXP2F(acc[jt][r] - mnew);    // masked -> 0
                    ps += p;
                    pa[jt >> 1][(jt & 1) * 4 + r] = (_Float16)p;
                }
            ps += __shfl_xor(ps, 16);
            ps += __shfl_xor(ps, 32);

            if (grow) {
                float alpha = EXP2F(m - mnew);   // first real chunk -> 0
                s = s * alpha + ps;
                m = mnew;
                float alphaD[4];
                #pragma unroll
                for (int r = 0; r < 4; ++r)
                    alphaD[r] = __shfl(alpha, (lane & 48) | (4 * g + r));
                #pragma unroll
                for (int nt = 0; nt < 4; ++nt)
                    #pragma unroll
                    for (int r = 0; r < 4; ++r) accO[nt][r] *= alphaD[r];
            } else {
                s += ps;
            }

            #pragma unroll
            for (int st = 0; st < 2; ++st) {
                #pragma unroll
                for (int nt = 0; nt < 4; ++nt) {
                    f16x8 vb = *(const f16x8*)&Vt[nt * 16 + c][ch * 64 + st * 32 + 8 * g];
                    accO[nt] = __builtin_amdgcn_mfma_f32_16x16x32_f16(pa[st], vb, accO[nt], 0, 0, 0);
                }
            }
        }
    };

    // ---- schedule: Qraw -> stage(h0) -> ropeQ -> sync -> compute(h0) -> sync ->
    //      stage(h1) -> sync -> compute(h1, causal) -> epilogue ----
    float4 qr[4];
    {
        const float* p = qg + (rowb + ww * 128 + qrow) * 64 + 8 * g;
        qr[0] = *(const float4*)p;
        qr[1] = *(const float4*)(p + 4);
        qr[2] = *(const float4*)(p + 32);
        qr[3] = *(const float4*)(p + 36);
    }

    if (ww != 0) stage(0);

    f16x8 qA, qB;
    {
        const float tq = (float)(128 + qrow);
        float ra[8] = {qr[0].x,qr[0].y,qr[0].z,qr[0].w,qr[1].x,qr[1].y,qr[1].z,qr[1].w};
        float rb[8] = {qr[2].x,qr[2].y,qr[2].z,qr[2].w,qr[3].x,qr[3].y,qr[3].z,qr[3].w};
        #pragma unroll
        for (int u = 0; u < 8; ++u) {
            float sn, cs; __sincosf(tq * invfQ[u], &sn, &cs);
            float a = ra[u] * QSCALE, b = rb[u] * QSCALE;
            qA[u] = (_Float16)(a * cs - b * sn);
            qB[u] = (_Float16)(b * cs + a * sn);
        }
    }

    if (ww != 0) {
        __syncthreads();
        computeHalf(false, qA, qB);
        __syncthreads();                 // slot reads done before overwrite
    }

    stage(1);
    __syncthreads();
    computeHalf(true, qA, qB);

    // ---- epilogue: 1/s (c-layout) -> row-layout, store ----
    float rcp = 1.0f / s;
    float rcpD[4];
    #pragma unroll
    for (int r = 0; r < 4; ++r)
        rcpD[r] = __shfl(rcp, (lane & 48) | (4 * g + r));

    float* op = outg + (rowb + ww * 128 + wv * 16) * 64;
    #pragma unroll
    for (int nt = 0; nt < 4; ++nt)
        #pragma unroll
        for (int r = 0; r < 4; ++r)
            op[(size_t)(4 * g + r) * 64 + nt * 16 + c] = accO[nt][r] * rcpD[r];
}

extern "C" void kernel_launch(void* const* d_in, const int* in_sizes, int n_in,
                              void* d_out, int out_size, void* d_ws, size_t ws_size,
                              hipStream_t stream) {
    (void)in_sizes; (void)n_in; (void)out_size; (void)d_ws; (void)ws_size;
    const float* q = (const float*)d_in[0];
    const float* k = (const float*)d_in[1];
    const float* v = (const float*)d_in[2];
    float* out = (float*)d_out;
    dim3 grid(32, 32);  // x = window, y = batch
    la_kernel<<<grid, BDIM, 0, stream>>>(q, k, v, out);
}

// Round 17
// 32.799 us; speedup vs baseline: 1.1948x; 1.1588x over previous
//
#include <hip/hip_runtime.h>
#include <hip/hip_bf16.h>

#define BDIM 512

typedef __attribute__((ext_vector_type(8))) _Float16 f16x8;
typedef __attribute__((ext_vector_type(4))) _Float16 f16x4;
typedef __attribute__((ext_vector_type(4))) float f32x4;

// native v_exp_f32 computes 2^x; __exp2f doesn't exist in HIP
#define EXP2F(x) __builtin_amdgcn_exp2f(x)

// Local windowed attention with RoPE. b=32, n=4096, d=64, WINDOW=128, 1 backward window.
// ONE BLOCK PER WINDOW-PAIR (RoPE relative-position invariance -> middle K/V half
// shared; block-common origin, t in [0,384)). 3 halves in 2 rolling LDS slots
// (72.7KB, 2 blocks/CU, launch_bounds(512,4) - the no-spill cell; R15/R16 falsified
// the occupancy axis: 43-57% occ was SLOWER than 30%).
// R17: FLAT SOFTMAX. Both halves of a window are LDS-resident when its compute runs,
// so the online/flash chunking (R13) is unnecessary: acc[16] holds the full 256-key
// score row; ONE max-reduce + one exp2 pass + one sum-reduce; no alpha rescale, no
// __all, no c->row alpha shuffles. R2 evidence: acc[16] compiles to 56 VGPR, no spill.
// Finer wave-uniform skips: second-half tile jt computed only if jt-8 <= wv (avg 3.5
// tiles skipped vs R13's chunk-level 2); diagonal mask is tile jt==8+wv with the
// wave-independent condition 4g+r > c (compile-time acc indices per scratch rule).
// Carried: swapped QK^T (stats c-layout, accO row-layout, 1/s shuffled c->row at the
// end), permuted Vt columns (PV B-operand = one ds_read_b128), exp2-domain scores
// (log2e folded into Q scale), Q loads issued before staging.
// Spill sentinel: WRITE_SIZE == output 32.8MB.
__global__ __launch_bounds__(512, 4)
void la_kernel(const float* __restrict__ qg, const float* __restrict__ kg,
               const float* __restrict__ vg, float* __restrict__ outg)
{
    __shared__ _Float16 Ks[2][128][72];   // 36864 B
    __shared__ _Float16 Vt[2][64][140];   // 35840 B   total 72704 B

    const int wp = blockIdx.x, bb = blockIdx.y;
    const int tid = threadIdx.x;
    const int wv = tid >> 6, lane = tid & 63, g = lane >> 4, c = lane & 15;
    const int base = 256 * wp - 128;      // phys row of t=0 (block-common origin)
    const float NEG = -3.0e38f;
    const float NLT32 = -0.28782313662425572f;   // -ln(10000)/32
    const float QSCALE = 0.125f * 1.4426950408889634f;  // d^-0.5 * log2(e)
    const size_t rowb = (size_t)bb * 4096;

    // hoisted inverse frequencies
    const int cbK = (tid & 7) << 2;
    float invfK[4];
    #pragma unroll
    for (int u = 0; u < 4; ++u) invfK[u] = __expf((float)(cbK + u) * NLT32);
    float invfQ[8];
    #pragma unroll
    for (int u = 0; u < 8; ++u) invfQ[u] = __expf((float)(8 * g + u) * NLT32);

    const int jqV = tid >> 4, eqV = tid & 15;
    const int colbV = ((jqV & 24) << 2) + 8 * (jqV & 3) + 4 * ((jqV >> 2) & 1);

    const int qrow = wv * 16 + c;

    // ---- stage physical half mm (t = 128*mm + jloc) into slot mm&1 ----
    auto stage = [&](int mm) {
        int sl = mm & 1;
        #pragma unroll
        for (int it = 0; it < 2; ++it) {
            int j = (tid + it * 512) >> 3;         // 0..127
            int t = 128 * mm + j;
            const float* p = kg + (rowb + base + t) * 64 + cbK;
            float4 x1 = *(const float4*)p;
            float4 x2 = *(const float4*)(p + 32);
            const float* x1p = &x1.x;
            const float* x2p = &x2.x;
            f16x4 lo, hi;
            #pragma unroll
            for (int u = 0; u < 4; ++u) {
                float sn, cs; __sincosf((float)t * invfK[u], &sn, &cs);
                lo[u] = (_Float16)(x1p[u] * cs - x2p[u] * sn);
                hi[u] = (_Float16)(x2p[u] * cs + x1p[u] * sn);
            }
            *(f16x4*)&Ks[sl][j][cbK]      = lo;
            *(f16x4*)&Ks[sl][j][cbK + 32] = hi;
        }
        float4 x[4];
        #pragma unroll
        for (int w = 0; w < 4; ++w)
            x[w] = *(const float4*)(vg + (rowb + base + 128 * mm + 4 * jqV + w) * 64 + 4 * eqV);
        #pragma unroll
        for (int u = 0; u < 4; ++u) {
            f16x4 o;
            o[0] = (_Float16)((const float*)&x[0])[u];
            o[1] = (_Float16)((const float*)&x[1])[u];
            o[2] = (_Float16)((const float*)&x[2])[u];
            o[3] = (_Float16)((const float*)&x[3])[u];
            *(f16x4*)&Vt[sl][4 * eqV + u][colbV] = o;
        }
    };

    // ---- Q: split load / RoPE ----
    auto loadQraw = [&](int wi, float4* qr) {
        const int tq = 128 * (wi + 1) + qrow;
        const float* p = qg + (rowb + base + tq) * 64 + 8 * g;
        qr[0] = *(const float4*)p;
        qr[1] = *(const float4*)(p + 4);
        qr[2] = *(const float4*)(p + 32);
        qr[3] = *(const float4*)(p + 36);
    };
    auto ropeQ = [&](int wi, const float4* qr, f16x8& qa0, f16x8& qa1) {
        const int tq = 128 * (wi + 1) + qrow;
        float ra[8] = {qr[0].x,qr[0].y,qr[0].z,qr[0].w,qr[1].x,qr[1].y,qr[1].z,qr[1].w};
        float rb[8] = {qr[2].x,qr[2].y,qr[2].z,qr[2].w,qr[3].x,qr[3].y,qr[3].z,qr[3].w};
        #pragma unroll
        for (int u = 0; u < 8; ++u) {
            float sn, cs; __sincosf((float)tq * invfQ[u], &sn, &cs);
            float a = ra[u] * QSCALE, b = rb[u] * QSCALE;
            qa0[u] = (_Float16)(a * cs - b * sn);
            qa1[u] = (_Float16)(b * cs + a * sn);
        }
    };

    // ---- compute one window (wi), flat softmax over 16 j-tiles ----
    // jt 0..7  -> half wi   (slot wi&1),     no causal mask
    // jt 8..15 -> half wi+1 (slot (wi+1)&1), causal; computed iff jt-8 <= wv;
    //            diagonal tile jt == 8+wv partially masked where 4g+r > c
    auto computeWin = [&](int wi, f16x8 qa0, f16x8 qa1) {
        const bool skipFirst = (wp == 0 && wi == 0);  // padding half
        const int sl0 = wi & 1, sl1 = (wi + 1) & 1;

        f32x4 acc[16];
        #pragma unroll
        for (int jt = 0; jt < 16; ++jt) acc[jt] = (f32x4){0.f,0.f,0.f,0.f};

        #pragma unroll
        for (int jt = 0; jt < 16; ++jt) {
            const bool doit = (jt < 8) ? (!skipFirst) : ((jt - 8) <= wv);
            if (doit) {
                const int sl = (jt < 8) ? sl0 : sl1;
                const int row = (jt & 7) * 16 + c;
                f16x8 kb0 = *(const f16x8*)&Ks[sl][row][8 * g];
                f16x8 kb1 = *(const f16x8*)&Ks[sl][row][32 + 8 * g];
                acc[jt] = __builtin_amdgcn_mfma_f32_16x16x32_f16(kb0, qa0, acc[jt], 0, 0, 0);
                acc[jt] = __builtin_amdgcn_mfma_f32_16x16x32_f16(kb1, qa1, acc[jt], 0, 0, 0);
            }
        }

        // mask (diag tile only) + max over computed tiles
        float mx = NEG;
        #pragma unroll
        for (int jt = 0; jt < 16; ++jt) {
            const bool doit = (jt < 8) ? (!skipFirst) : ((jt - 8) <= wv);
            if (doit) {
                if (jt >= 8 && jt == 8 + wv) {
                    #pragma unroll
                    for (int r = 0; r < 4; ++r)
                        if (4 * g + r > c) acc[jt][r] = NEG;
                }
                #pragma unroll
                for (int r = 0; r < 4; ++r) mx = fmaxf(mx, acc[jt][r]);
            }
        }
        mx = fmaxf(mx, __shfl_xor(mx, 16));
        mx = fmaxf(mx, __shfl_xor(mx, 32));

        // exp2 + sum + pack P fragments (skipped tiles stay 0)
        f16x8 pa[8];
        #pragma unroll
        for (int p8 = 0; p8 < 8; ++p8)
            pa[p8] = (f16x8){0.f,0.f,0.f,0.f,0.f,0.f,0.f,0.f};

        float s = 0.f;
        #pragma unroll
        for (int jt = 0; jt < 16; ++jt) {
            const bool doit = (jt < 8) ? (!skipFirst) : ((jt - 8) <= wv);
            if (doit) {
                #pragma unroll
                for (int r = 0; r < 4; ++r) {
                    float p = EXP2F(acc[jt][r] - mx);   // masked -> 0
                    s += p;
                    pa[jt >> 1][(jt & 1) * 4 + r] = (_Float16)p;
                }
            }
        }
        s += __shfl_xor(s, 16);
        s += __shfl_xor(s, 32);

        // PV: 8 j-groups of 32; skip groups whose P is entirely zero
        f32x4 accO[4];
        #pragma unroll
        for (int nt = 0; nt < 4; ++nt) accO[nt] = (f32x4){0.f,0.f,0.f,0.f};

        #pragma unroll
        for (int st = 0; st < 8; ++st) {
            const bool doit = (st < 4) ? (!skipFirst) : ((2 * st - 8) <= wv);
            if (doit) {
                const int sl = (st < 4) ? sl0 : sl1;
                #pragma unroll
                for (int nt = 0; nt < 4; ++nt) {
                    f16x8 vb = *(const f16x8*)&Vt[sl][nt * 16 + c][(st & 3) * 32 + 8 * g];
                    accO[nt] = __builtin_amdgcn_mfma_f32_16x16x32_f16(pa[st], vb, accO[nt], 0, 0, 0);
                }
            }
        }

        // epilogue: 1/s (c-layout) -> row-layout, store
        float rcp = 1.0f / s;
        float rcpD[4];
        #pragma unroll
        for (int r = 0; r < 4; ++r)
            rcpD[r] = __shfl(rcp, (lane & 48) | (4 * g + r));

        float* op = outg + (rowb + base + 128 * (wi + 1) + wv * 16) * 64;
        #pragma unroll
        for (int nt = 0; nt < 4; ++nt)
            #pragma unroll
            for (int r = 0; r < 4; ++r)
                op[(size_t)(4 * g + r) * 64 + nt * 16 + c] = accO[nt][r] * rcpD[r];
    };

    // ---- schedule (R13 verbatim): Qraw(0) -> stage P0,P1 -> ropeQ(0) -> sync ->
    //      win0 -> Qraw(1) -> sync -> stage P2 -> ropeQ(1) -> sync -> win1 ----
    float4 qr[4];
    loadQraw(0, qr);                      // issued first; hidden under staging waits
    if (wp > 0) stage(0);
    stage(1);
    f16x8 qA, qB;
    ropeQ(0, qr, qA, qB);
    __syncthreads();
    computeWin(0, qA, qB);
    loadQraw(1, qr);                      // issue win1's Q before the barrier
    __syncthreads();                      // all reads of slot0 done
    stage(2);
    ropeQ(1, qr, qA, qB);
    __syncthreads();
    computeWin(1, qA, qB);
}

extern "C" void kernel_launch(void* const* d_in, const int* in_sizes, int n_in,
                              void* d_out, int out_size, void* d_ws, size_t ws_size,
                              hipStream_t stream) {
    (void)in_sizes; (void)n_in; (void)out_size; (void)d_ws; (void)ws_size;
    const float* q = (const float*)d_in[0];
    const float* k = (const float*)d_in[1];
    const float* v = (const float*)d_in[2];
    float* out = (float*)d_out;
    dim3 grid(16, 32);  // x = window-pair, y = batch
    la_kernel<<<grid, BDIM, 0, stream>>>(q, k, v, out);
}

// Round 18
// 32.536 us; speedup vs baseline: 1.2044x; 1.0081x over previous
//
#include <hip/hip_runtime.h>
#include <hip/hip_bf16.h>

#define BDIM 512

typedef __attribute__((ext_vector_type(8))) _Float16 f16x8;
typedef __attribute__((ext_vector_type(4))) _Float16 f16x4;
typedef __attribute__((ext_vector_type(4))) float f32x4;

// native v_exp_f32 computes 2^x; __exp2f doesn't exist in HIP
#define EXP2F(x) __builtin_amdgcn_exp2f(x)

// Local windowed attention with RoPE. b=32, n=4096, d=64, WINDOW=128, 1 backward window.
// ONE BLOCK PER WINDOW-PAIR (RoPE relative-position invariance -> middle K/V half
// shared; block-common origin, t in [0,384)). 3 halves in 2 rolling LDS slots
// (72.7KB, 2 blocks/CU, launch_bounds(512,4); occupancy axis falsified R15/R16).
// R18 = R17 flat softmax + FUSED exp/pack/PV: after the single max-reduce, each
// 32-key j-group is exp2'd, packed to one f16x8 and fed straight to its 4 PV MFMAs
// (s accumulated in the same pass; PV needs only mx). Kills the pa[8] live array
// that caused R17's 0.5MB spill, and overlaps exp2(group k+1) with PV MFMA(group k).
// acc has no zero-init (first MFMA takes a literal zero C). Only the boundary
// group's odd half-fragment is explicitly zeroed (the one skipped tile PV reads).
// Carried: swapped QK^T (stats c-layout, accO row-layout, 1/s shuffled c->row),
// permuted Vt columns (PV B-operand = one ds_read_b128), exp2-domain scores,
// tile-granular causal skips (jt-8 <= wv), diag mask 4g+r > c on tile 8+wv,
// Q loads issued before staging. Spill sentinel: WRITE_SIZE == output 32.8MB.
__global__ __launch_bounds__(512, 4)
void la_kernel(const float* __restrict__ qg, const float* __restrict__ kg,
               const float* __restrict__ vg, float* __restrict__ outg)
{
    __shared__ _Float16 Ks[2][128][72];   // 36864 B
    __shared__ _Float16 Vt[2][64][140];   // 35840 B   total 72704 B

    const int wp = blockIdx.x, bb = blockIdx.y;
    const int tid = threadIdx.x;
    const int wv = tid >> 6, lane = tid & 63, g = lane >> 4, c = lane & 15;
    const int base = 256 * wp - 128;      // phys row of t=0 (block-common origin)
    const float NEG = -3.0e38f;
    const float NLT32 = -0.28782313662425572f;   // -ln(10000)/32
    const float QSCALE = 0.125f * 1.4426950408889634f;  // d^-0.5 * log2(e)
    const size_t rowb = (size_t)bb * 4096;

    // hoisted inverse frequencies
    const int cbK = (tid & 7) << 2;
    float invfK[4];
    #pragma unroll
    for (int u = 0; u < 4; ++u) invfK[u] = __expf((float)(cbK + u) * NLT32);
    float invfQ[8];
    #pragma unroll
    for (int u = 0; u < 8; ++u) invfQ[u] = __expf((float)(8 * g + u) * NLT32);

    const int jqV = tid >> 4, eqV = tid & 15;
    const int colbV = ((jqV & 24) << 2) + 8 * (jqV & 3) + 4 * ((jqV >> 2) & 1);

    const int qrow = wv * 16 + c;

    // ---- stage physical half mm (t = 128*mm + jloc) into slot mm&1 ----
    auto stage = [&](int mm) {
        int sl = mm & 1;
        #pragma unroll
        for (int it = 0; it < 2; ++it) {
            int j = (tid + it * 512) >> 3;         // 0..127
            int t = 128 * mm + j;
            const float* p = kg + (rowb + base + t) * 64 + cbK;
            float4 x1 = *(const float4*)p;
            float4 x2 = *(const float4*)(p + 32);
            const float* x1p = &x1.x;
            const float* x2p = &x2.x;
            f16x4 lo, hi;
            #pragma unroll
            for (int u = 0; u < 4; ++u) {
                float sn, cs; __sincosf((float)t * invfK[u], &sn, &cs);
                lo[u] = (_Float16)(x1p[u] * cs - x2p[u] * sn);
                hi[u] = (_Float16)(x2p[u] * cs + x1p[u] * sn);
            }
            *(f16x4*)&Ks[sl][j][cbK]      = lo;
            *(f16x4*)&Ks[sl][j][cbK + 32] = hi;
        }
        float4 x[4];
        #pragma unroll
        for (int w = 0; w < 4; ++w)
            x[w] = *(const float4*)(vg + (rowb + base + 128 * mm + 4 * jqV + w) * 64 + 4 * eqV);
        #pragma unroll
        for (int u = 0; u < 4; ++u) {
            f16x4 o;
            o[0] = (_Float16)((const float*)&x[0])[u];
            o[1] = (_Float16)((const float*)&x[1])[u];
            o[2] = (_Float16)((const float*)&x[2])[u];
            o[3] = (_Float16)((const float*)&x[3])[u];
            *(f16x4*)&Vt[sl][4 * eqV + u][colbV] = o;
        }
    };

    // ---- Q: split load / RoPE ----
    auto loadQraw = [&](int wi, float4* qr) {
        const int tq = 128 * (wi + 1) + qrow;
        const float* p = qg + (rowb + base + tq) * 64 + 8 * g;
        qr[0] = *(const float4*)p;
        qr[1] = *(const float4*)(p + 4);
        qr[2] = *(const float4*)(p + 32);
        qr[3] = *(const float4*)(p + 36);
    };
    auto ropeQ = [&](int wi, const float4* qr, f16x8& qa0, f16x8& qa1) {
        const int tq = 128 * (wi + 1) + qrow;
        float ra[8] = {qr[0].x,qr[0].y,qr[0].z,qr[0].w,qr[1].x,qr[1].y,qr[1].z,qr[1].w};
        float rb[8] = {qr[2].x,qr[2].y,qr[2].z,qr[2].w,qr[3].x,qr[3].y,qr[3].z,qr[3].w};
        #pragma unroll
        for (int u = 0; u < 8; ++u) {
            float sn, cs; __sincosf((float)tq * invfQ[u], &sn, &cs);
            float a = ra[u] * QSCALE, b = rb[u] * QSCALE;
            qa0[u] = (_Float16)(a * cs - b * sn);
            qa1[u] = (_Float16)(b * cs + a * sn);
        }
    };

    // ---- compute one window (wi), flat softmax, fused exp+pack+PV ----
    // jt 0..7  -> half wi   (slot wi&1),     no causal mask
    // jt 8..15 -> half wi+1 (slot (wi+1)&1), causal; computed iff jt-8 <= wv;
    //            diagonal tile jt == 8+wv partially masked where 4g+r > c
    auto computeWin = [&](int wi, f16x8 qa0, f16x8 qa1) {
        const bool skipFirst = (wp == 0 && wi == 0);  // padding half
        const int sl0 = wi & 1, sl1 = (wi + 1) & 1;
        const f32x4 CZERO = (f32x4){0.f, 0.f, 0.f, 0.f};

        f32x4 acc[16];
        #pragma unroll
        for (int jt = 0; jt < 16; ++jt) {
            const bool doit = (jt < 8) ? (!skipFirst) : ((jt - 8) <= wv);
            if (doit) {
                const int sl = (jt < 8) ? sl0 : sl1;
                const int row = (jt & 7) * 16 + c;
                f16x8 kb0 = *(const f16x8*)&Ks[sl][row][8 * g];
                f16x8 kb1 = *(const f16x8*)&Ks[sl][row][32 + 8 * g];
                acc[jt] = __builtin_amdgcn_mfma_f32_16x16x32_f16(kb0, qa0, CZERO, 0, 0, 0);
                acc[jt] = __builtin_amdgcn_mfma_f32_16x16x32_f16(kb1, qa1, acc[jt], 0, 0, 0);
            }
        }

        // mask (diag tile only) + max over computed tiles
        float mx = NEG;
        #pragma unroll
        for (int jt = 0; jt < 16; ++jt) {
            const bool doit = (jt < 8) ? (!skipFirst) : ((jt - 8) <= wv);
            if (doit) {
                if (jt >= 8 && jt == 8 + wv) {
                    #pragma unroll
                    for (int r = 0; r < 4; ++r)
                        if (4 * g + r > c) acc[jt][r] = NEG;
                }
                #pragma unroll
                for (int r = 0; r < 4; ++r) mx = fmaxf(mx, acc[jt][r]);
            }
        }
        mx = fmaxf(mx, __shfl_xor(mx, 16));
        mx = fmaxf(mx, __shfl_xor(mx, 32));

        // fused: per 32-key group, exp2 + pack ONE fragment + 4 PV MFMAs; s on the fly
        f32x4 accO[4];
        #pragma unroll
        for (int nt = 0; nt < 4; ++nt) accO[nt] = CZERO;

        float s = 0.f;
        #pragma unroll
        for (int st = 0; st < 8; ++st) {
            const bool grp = (st < 4) ? (!skipFirst) : ((2 * st - 8) <= wv);
            if (grp) {
                f16x8 pa;
                #pragma unroll
                for (int r = 0; r < 4; ++r) {
                    float p = EXP2F(acc[2 * st][r] - mx);     // masked -> 0
                    s += p;
                    pa[r] = (_Float16)p;
                }
                const bool oddOk = (st < 4) || ((2 * st - 7) <= wv);
                if (oddOk) {
                    #pragma unroll
                    for (int r = 0; r < 4; ++r) {
                        float p = EXP2F(acc[2 * st + 1][r] - mx);
                        s += p;
                        pa[4 + r] = (_Float16)p;
                    }
                } else {
                    #pragma unroll
                    for (int r = 0; r < 4; ++r) pa[4 + r] = (_Float16)0.f;
                }
                const int sl = (st < 4) ? sl0 : sl1;
                #pragma unroll
                for (int nt = 0; nt < 4; ++nt) {
                    f16x8 vb = *(const f16x8*)&Vt[sl][nt * 16 + c][(st & 3) * 32 + 8 * g];
                    accO[nt] = __builtin_amdgcn_mfma_f32_16x16x32_f16(pa, vb, accO[nt], 0, 0, 0);
                }
            }
        }
        s += __shfl_xor(s, 16);
        s += __shfl_xor(s, 32);

        // epilogue: 1/s (c-layout) -> row-layout, store
        float rcp = 1.0f / s;
        float rcpD[4];
        #pragma unroll
        for (int r = 0; r < 4; ++r)
            rcpD[r] = __shfl(rcp, (lane & 48) | (4 * g + r));

        float* op = outg + (rowb + base + 128 * (wi + 1) + wv * 16) * 64;
        #pragma unroll
        for (int nt = 0; nt < 4; ++nt)
            #pragma unroll
            for (int r = 0; r < 4; ++r)
                op[(size_t)(4 * g + r) * 64 + nt * 16 + c] = accO[nt][r] * rcpD[r];
    };

    // ---- schedule (R13 verbatim): Qraw(0) -> stage P0,P1 -> ropeQ(0) -> sync ->
    //      win0 -> Qraw(1) -> sync -> stage P2 -> ropeQ(1) -> sync -> win1 ----
    float4 qr[4];
    loadQraw(0, qr);                      // issued first; hidden under staging waits
    if (wp > 0) stage(0);
    stage(1);
    f16x8 qA, qB;
    ropeQ(0, qr, qA, qB);
    __syncthreads();
    computeWin(0, qA, qB);
    loadQraw(1, qr);                      // issue win1's Q before the barrier
    __syncthreads();                      // all reads of slot0 done
    stage(2);
    ropeQ(1, qr, qA, qB);
    __syncthreads();
    computeWin(1, qA, qB);
}

extern "C" void kernel_launch(void* const* d_in, const int* in_sizes, int n_in,
                              void* d_out, int out_size, void* d_ws, size_t ws_size,
                              hipStream_t stream) {
    (void)in_sizes; (void)n_in; (void)out_size; (void)d_ws; (void)ws_size;
    const float* q = (const float*)d_in[0];
    const float* k = (const float*)d_in[1];
    const float* v = (const float*)d_in[2];
    float* out = (float*)d_out;
    dim3 grid(16, 32);  // x = window-pair, y = batch
    la_kernel<<<grid, BDIM, 0, stream>>>(q, k, v, out);
}